// Round 1
// baseline (364.220 us; speedup 1.0000x reference)
//
#include <hip/hip_runtime.h>
#include <hip/hip_bf16.h>

#define M_ 501
#define K_PAD 1024
#define NTOT 384
#define T_ 512
#define DT_ 0.01f

typedef __attribute__((ext_vector_type(8))) __bf16 bf16x8;
typedef __attribute__((ext_vector_type(4))) float f32x4;

// ---------------- P1: pack X = [E | nu | 0pad] as bf16, B x 1024 row-major ----
__global__ void build_x(const float* __restrict__ E, const float* __restrict__ nu,
                        __hip_bfloat16* __restrict__ Xbf, int B) {
    long long idx = (long long)blockIdx.x * 256 + threadIdx.x;
    if (idx >= (long long)B * K_PAD) return;
    int b = (int)(idx >> 10), k = (int)(idx & 1023);
    float v = 0.f;
    if (k < M_)        v = E[(size_t)b * M_ + k];
    else if (k < 2*M_) v = nu[(size_t)b * M_ + (k - M_)];
    Xbf[idx] = __float2bfloat16(v);
}

// ---------------- P2: pack W1comb (1024 x 384) pre-swizzled into MFMA B-fragment order
// element layout: [((k0*24 + nt)*64 + lane)*8 + e]  where k = k0*32 + (lane>>4)*8 + e,
//                 n = nt*16 + (lane&15)
__global__ void build_w(const float* __restrict__ Ew1, const float* __restrict__ bw1,
                        const float* __restrict__ nw1, __hip_bfloat16* __restrict__ Wswz) {
    int idx = blockIdx.x * 256 + threadIdx.x;       // total 32*24*64*8 = 393216
    if (idx >= 32 * 24 * 64 * 8) return;
    int e  = idx & 7;
    int l  = (idx >> 3) & 63;
    int t  = idx >> 9;                               // k0*24 + nt
    int nt = t % 24, k0 = t / 24;
    int k  = k0 * 32 + ((l >> 4) << 3) + e;
    int n  = nt * 16 + (l & 15);
    float v = 0.f;
    if (n < 128)      { if (k < 2*M_)             v = Ew1[k * 128 + n]; }
    else if (n < 256) { if (k < 2*M_)             v = bw1[k * 128 + (n - 128)]; }
    else              { if (k >= M_ && k < 2*M_)  v = nw1[(k - M_) * 128 + (n - 256)]; }
    Wswz[idx] = __float2bfloat16(v);
}

// ---------------- GEMM + fused second layer ---------------------------------
// Each wave: 16 rows (b) x all 384 cols. Block = 4 waves = 64 rows.
__global__ __launch_bounds__(256) void mlp_gemm(
    const __hip_bfloat16* __restrict__ Xbf, const __hip_bfloat16* __restrict__ Wswz,
    const float* __restrict__ Eb1, const float* __restrict__ bb1, const float* __restrict__ nb1,
    const float* __restrict__ Ew2, const float* __restrict__ bw2, const float* __restrict__ nw2,
    const float* __restrict__ Eb2, const float* __restrict__ bb2, const float* __restrict__ nb2,
    float* __restrict__ Emod, float* __restrict__ nuv, float* __restrict__ beta)
{
    int wid = threadIdx.x >> 6, l = threadIdx.x & 63;
    int btile = blockIdx.x * 4 + wid;               // 16-row tile index
    const int c = l & 15, g = l >> 4;

    size_t xbase = (size_t)(btile * 16 + c) * K_PAD + ((size_t)g << 3);
    const bf16x8* wbase = (const bf16x8*)Wswz;

    f32x4 acc[24];
    #pragma unroll
    for (int i = 0; i < 24; i++) acc[i] = (f32x4){0.f, 0.f, 0.f, 0.f};

    for (int k0 = 0; k0 < 32; k0++) {
        bf16x8 afrag = *(const bf16x8*)(Xbf + xbase + (size_t)k0 * 32);
        #pragma unroll
        for (int nt = 0; nt < 24; nt++) {
            bf16x8 bfrag = wbase[(size_t)(k0 * 24 + nt) * 64 + l];
            acc[nt] = __builtin_amdgcn_mfma_f32_16x16x32_bf16(afrag, bfrag, acc[nt], 0, 0, 0);
        }
    }

    // Epilogue: h = softplus(acc + b1); dot with w2 per MLP.
    // D layout: row = g*4 + r (b within tile), col = c (n within n-tile).
    float s[3][4];
    #pragma unroll
    for (int m = 0; m < 3; m++)
        #pragma unroll
        for (int r = 0; r < 4; r++) s[m][r] = 0.f;

    #pragma unroll
    for (int nt = 0; nt < 24; nt++) {
        const int mlp = nt >> 3;                    // 0:E 1:beta 2:nu (compile-time)
        int jj = (nt * 16 + c) & 127;               // col within this MLP's 128 hidden
        float b1 = (mlp == 0) ? Eb1[jj] : (mlp == 1) ? bb1[jj] : nb1[jj];
        float w2 = (mlp == 0) ? Ew2[jj] : (mlp == 1) ? bw2[jj] : nw2[jj];
        #pragma unroll
        for (int r = 0; r < 4; r++) {
            float x = acc[nt][r] + b1;
            float h = fmaxf(x, 0.f) + log1pf(expf(-fabsf(x)));   // softplus, stable
            float v = h * w2;
            v += __shfl_xor(v, 1);
            v += __shfl_xor(v, 2);
            v += __shfl_xor(v, 4);
            v += __shfl_xor(v, 8);
            s[mlp][r] += v;
        }
    }

    if (c == 0) {
        float eb2 = Eb2[0], bb2s = bb2[0], nb2s = nb2[0];
        #pragma unroll
        for (int r = 0; r < 4; r++) {
            int b = btile * 16 + g * 4 + r;
            Emod[b] = expf(s[0][r] + eb2);
            float mb = s[1][r] + bb2s;
            beta[b]  = mb * mb * (1.f / 40000.f);
            float mn = s[2][r] + nb2s;
            nuv[b]   = expf(mn * mn * (1.f / 40000.f));
        }
    }
}

// ---------------- Scan: one wave per row b, lane i owns t in [8i, 8i+8) ------
__global__ __launch_bounds__(256) void scan_k(
    const float* __restrict__ e, const float* __restrict__ ed,
    const float* __restrict__ Emod, const float* __restrict__ nuv, const float* __restrict__ beta,
    float* __restrict__ stress, float* __restrict__ xiout)
{
    int lane = threadIdx.x & 63;
    int b = blockIdx.x * 4 + (threadIdx.x >> 6);
    float Em = Emod[b], nv = nuv[b], bt = beta[b];
    float cc = DT_ * bt;
    float a  = 1.f - cc;

    size_t base = (size_t)b * T_ + (size_t)lane * 8;
    float4 e0 = *(const float4*)(e + base),  e1 = *(const float4*)(e + base + 4);
    float4 d0 = *(const float4*)(ed + base), d1 = *(const float4*)(ed + base + 4);
    float ev[8] = {e0.x, e0.y, e0.z, e0.w, e1.x, e1.y, e1.z, e1.w};
    float dv[8] = {d0.x, d0.y, d0.z, d0.w, d1.x, d1.y, d1.z, d1.w};

    // local segment: xi_out = A*xi_in + cc*S,  A = a^8, S = sum a^(7-s) e_s
    float S = 0.f;
    #pragma unroll
    for (int j = 0; j < 8; j++) S = a * S + ev[j];
    float a2 = a * a, a4 = a2 * a2, A = a4 * a4;

    // Kogge-Stone inclusive scan over 64 lanes: (A1,S1) then (A2,S2) -> (A1*A2, S1*A2+S2)
    #pragma unroll
    for (int d = 1; d < 64; d <<= 1) {
        float Su = __shfl_up(S, d);
        float Au = __shfl_up(A, d);
        if (lane >= d) { S = Su * A + S; A = Au * A; }
    }
    float Sp = __shfl_up(S, 1);
    float xi = (lane == 0) ? 0.f : cc * Sp;

    float st[8], xo[8];
    #pragma unroll
    for (int j = 0; j < 8; j++) {
        xo[j] = xi;
        float q = ev[j] - xi;
        st[j] = Em * ev[j] + q + nv * dv[j];       // stress_t
        xi = xi + cc * q;                           // exact reference update
    }
    *(float4*)(stress + base)     = (float4){st[0], st[1], st[2], st[3]};
    *(float4*)(stress + base + 4) = (float4){st[4], st[5], st[6], st[7]};
    *(float4*)(xiout + base)      = (float4){xo[0], xo[1], xo[2], xo[3]};
    *(float4*)(xiout + base + 4)  = (float4){xo[4], xo[5], xo[6], xo[7]};
}

extern "C" void kernel_launch(void* const* d_in, const int* in_sizes, int n_in,
                              void* d_out, int out_size, void* d_ws, size_t ws_size,
                              hipStream_t stream) {
    const float* e   = (const float*)d_in[0];
    const float* ed  = (const float*)d_in[1];
    const float* E   = (const float*)d_in[2];
    const float* nu  = (const float*)d_in[3];
    const float* Ew1 = (const float*)d_in[4];
    const float* Eb1 = (const float*)d_in[5];
    const float* Ew2 = (const float*)d_in[6];
    const float* Eb2 = (const float*)d_in[7];
    const float* nw1 = (const float*)d_in[8];
    const float* nb1 = (const float*)d_in[9];
    const float* nw2 = (const float*)d_in[10];
    const float* nb2 = (const float*)d_in[11];
    const float* bw1 = (const float*)d_in[12];
    const float* bb1 = (const float*)d_in[13];
    const float* bw2 = (const float*)d_in[14];
    const float* bb2 = (const float*)d_in[15];

    int B = in_sizes[2] / M_;                       // 32768

    char* ws = (char*)d_ws;
    __hip_bfloat16* Xbf  = (__hip_bfloat16*)ws;                                   // B*1024*2 bytes
    __hip_bfloat16* Wswz = (__hip_bfloat16*)(ws + (size_t)B * K_PAD * 2);         // 786432 bytes
    float* Emod = (float*)(ws + (size_t)B * K_PAD * 2 + (size_t)K_PAD * NTOT * 2);
    float* nuv  = Emod + B;
    float* beta = nuv + B;

    long long nx = (long long)B * K_PAD;
    build_x<<<(int)((nx + 255) / 256), 256, 0, stream>>>(E, nu, Xbf, B);
    build_w<<<(K_PAD * NTOT + 255) / 256, 256, 0, stream>>>(Ew1, bw1, nw1, Wswz);
    mlp_gemm<<<B / 64, 256, 0, stream>>>(Xbf, Wswz, Eb1, bb1, nb1, Ew2, bw2, nw2,
                                         Eb2, bb2, nb2, Emod, nuv, beta);
    float* stress = (float*)d_out;
    float* xiout  = stress + (size_t)B * T_;
    scan_k<<<B / 4, 256, 0, stream>>>(e, ed, Emod, nuv, beta, stress, xiout);
}

// Round 2
// 226.210 us; speedup vs baseline: 1.6101x; 1.6101x over previous
//
#include <hip/hip_runtime.h>
#include <hip/hip_bf16.h>

#define M_ 501
#define K_PAD 1024
#define NTOT 384
#define T_ 512
#define DT_ 0.01f

typedef __attribute__((ext_vector_type(8))) __bf16 bf16x8;
typedef __attribute__((ext_vector_type(4))) float f32x4;

// ---------------- P1: pack X k-major tiled: Xt[k0][b][kk], k = k0*32+kk ------
__global__ void build_x(const float* __restrict__ E, const float* __restrict__ nu,
                        __hip_bfloat16* __restrict__ Xt, int B) {
    long long idx = (long long)blockIdx.x * 256 + threadIdx.x;
    if (idx >= (long long)B * K_PAD) return;
    int b = (int)(idx >> 10), k = (int)(idx & 1023);
    float v = 0.f;
    if (k < M_)        v = E[(size_t)b * M_ + k];
    else if (k < 2*M_) v = nu[(size_t)b * M_ + (k - M_)];
    Xt[((size_t)(k >> 5) * B + b) * 32 + (k & 31)] = __float2bfloat16(v);
}

// ---------------- P2: pack W1comb (1024 x 384) pre-swizzled into MFMA B-fragment order
// element layout: [((k0*24 + nt)*64 + lane)*8 + e]  where k = k0*32 + (lane>>4)*8 + e,
//                 n = nt*16 + (lane&15)
__global__ void build_w(const float* __restrict__ Ew1, const float* __restrict__ bw1,
                        const float* __restrict__ nw1, __hip_bfloat16* __restrict__ Wswz) {
    int idx = blockIdx.x * 256 + threadIdx.x;       // total 32*24*64*8 = 393216
    if (idx >= 32 * 24 * 64 * 8) return;
    int e  = idx & 7;
    int l  = (idx >> 3) & 63;
    int t  = idx >> 9;                               // k0*24 + nt
    int nt = t % 24, k0 = t / 24;
    int k  = k0 * 32 + ((l >> 4) << 3) + e;
    int n  = nt * 16 + (l & 15);
    float v = 0.f;
    if (n < 128)      { if (k < 2*M_)             v = Ew1[k * 128 + n]; }
    else if (n < 256) { if (k < 2*M_)             v = bw1[k * 128 + (n - 128)]; }
    else              { if (k >= M_ && k < 2*M_)  v = nw1[(k - M_) * 128 + (n - 256)]; }
    Wswz[idx] = __float2bfloat16(v);
}

// ---------------- GEMM + fused second layer ---------------------------------
// Block = 4 waves = 64 rows. Each wave: all 64 rows (4 A-frags) x 96 cols (6 n-tiles).
__global__ __launch_bounds__(256, 2) void mlp_gemm(
    const __hip_bfloat16* __restrict__ Xt, const __hip_bfloat16* __restrict__ Wswz,
    const float* __restrict__ Eb1, const float* __restrict__ bb1, const float* __restrict__ nb1,
    const float* __restrict__ Ew2, const float* __restrict__ bw2, const float* __restrict__ nw2,
    const float* __restrict__ Eb2, const float* __restrict__ bb2, const float* __restrict__ nb2,
    float* __restrict__ Emod, float* __restrict__ nuv, float* __restrict__ beta, int B)
{
    const int wid = threadIdx.x >> 6, l = threadIdx.x & 63;
    const int c = l & 15, g = l >> 4;
    const int brow = blockIdx.x * 64;

    __shared__ float lds_s[3][64];
    if (threadIdx.x < 192) ((float*)lds_s)[threadIdx.x] = 0.f;

    const bf16x8* wbase = (const bf16x8*)Wswz;

    f32x4 acc[4][6];
    #pragma unroll
    for (int mi = 0; mi < 4; mi++)
        #pragma unroll
        for (int nt = 0; nt < 6; nt++) acc[mi][nt] = (f32x4){0.f, 0.f, 0.f, 0.f};

    for (int k0 = 0; k0 < 32; k0++) {
        bf16x8 af[4];
        #pragma unroll
        for (int mi = 0; mi < 4; mi++)
            af[mi] = *(const bf16x8*)(Xt + ((size_t)k0 * B + brow + mi * 16 + c) * 32 + g * 8);
        #pragma unroll
        for (int nt = 0; nt < 6; nt++) {
            bf16x8 bfrag = wbase[(size_t)(k0 * 24 + wid * 6 + nt) * 64 + l];
            #pragma unroll
            for (int mi = 0; mi < 4; mi++)
                acc[mi][nt] = __builtin_amdgcn_mfma_f32_16x16x32_bf16(af[mi], bfrag, acc[mi][nt], 0, 0, 0);
        }
    }
    __syncthreads();

    // Epilogue: h = softplus(acc + b1); dot with w2 per MLP; cross-wave via LDS atomics.
    // D layout: row (within mi's 16) = g*4 + r, col (within nt's 16) = c.
    #pragma unroll
    for (int nt = 0; nt < 6; nt++) {
        int gnt = wid * 6 + nt;
        int mlp = gnt >> 3;                          // 0:E 1:beta 2:nu
        int jj = (gnt * 16 + c) & 127;
        float b1 = (mlp == 0) ? Eb1[jj] : (mlp == 1) ? bb1[jj] : nb1[jj];
        float w2 = (mlp == 0) ? Ew2[jj] : (mlp == 1) ? bw2[jj] : nw2[jj];
        #pragma unroll
        for (int mi = 0; mi < 4; mi++) {
            #pragma unroll
            for (int r = 0; r < 4; r++) {
                float x = acc[mi][nt][r] + b1;
                float h = fmaxf(x, 0.f) + __logf(1.f + __expf(-fabsf(x)));
                float v = h * w2;
                v += __shfl_xor(v, 1);
                v += __shfl_xor(v, 2);
                v += __shfl_xor(v, 4);
                v += __shfl_xor(v, 8);
                if (c == 0) atomicAdd(&lds_s[mlp][mi * 16 + g * 4 + r], v);
            }
        }
    }
    __syncthreads();

    if (threadIdx.x < 64) {
        int b = brow + threadIdx.x;
        float s0 = lds_s[0][threadIdx.x], s1 = lds_s[1][threadIdx.x], s2 = lds_s[2][threadIdx.x];
        Emod[b] = __expf(s0 + Eb2[0]);
        float mb = s1 + bb2[0];
        beta[b]  = mb * mb * (1.f / 40000.f);
        float mn = s2 + nb2[0];
        nuv[b]   = __expf(mn * mn * (1.f / 40000.f));
    }
}

// ---------------- Scan: one wave per row b, lane i owns t in [8i, 8i+8) ------
__global__ __launch_bounds__(256) void scan_k(
    const float* __restrict__ e, const float* __restrict__ ed,
    const float* __restrict__ Emod, const float* __restrict__ nuv, const float* __restrict__ beta,
    float* __restrict__ stress, float* __restrict__ xiout)
{
    int lane = threadIdx.x & 63;
    int b = blockIdx.x * 4 + (threadIdx.x >> 6);
    float Em = Emod[b], nv = nuv[b], bt = beta[b];
    float cc = DT_ * bt;
    float a  = 1.f - cc;

    size_t base = (size_t)b * T_ + (size_t)lane * 8;
    float4 e0 = *(const float4*)(e + base),  e1 = *(const float4*)(e + base + 4);
    float4 d0 = *(const float4*)(ed + base), d1 = *(const float4*)(ed + base + 4);
    float ev[8] = {e0.x, e0.y, e0.z, e0.w, e1.x, e1.y, e1.z, e1.w};
    float dv[8] = {d0.x, d0.y, d0.z, d0.w, d1.x, d1.y, d1.z, d1.w};

    // local segment: xi_out = A*xi_in + cc*S,  A = a^8, S = sum a^(7-s) e_s
    float S = 0.f;
    #pragma unroll
    for (int j = 0; j < 8; j++) S = a * S + ev[j];
    float a2 = a * a, a4 = a2 * a2, A = a4 * a4;

    // Kogge-Stone inclusive scan over 64 lanes
    #pragma unroll
    for (int d = 1; d < 64; d <<= 1) {
        float Su = __shfl_up(S, d);
        float Au = __shfl_up(A, d);
        if (lane >= d) { S = Su * A + S; A = Au * A; }
    }
    float Sp = __shfl_up(S, 1);
    float xi = (lane == 0) ? 0.f : cc * Sp;

    float st[8], xo[8];
    #pragma unroll
    for (int j = 0; j < 8; j++) {
        xo[j] = xi;
        float q = ev[j] - xi;
        st[j] = Em * ev[j] + q + nv * dv[j];
        xi = xi + cc * q;
    }
    *(float4*)(stress + base)     = (float4){st[0], st[1], st[2], st[3]};
    *(float4*)(stress + base + 4) = (float4){st[4], st[5], st[6], st[7]};
    *(float4*)(xiout + base)      = (float4){xo[0], xo[1], xo[2], xo[3]};
    *(float4*)(xiout + base + 4)  = (float4){xo[4], xo[5], xo[6], xo[7]};
}

extern "C" void kernel_launch(void* const* d_in, const int* in_sizes, int n_in,
                              void* d_out, int out_size, void* d_ws, size_t ws_size,
                              hipStream_t stream) {
    const float* e   = (const float*)d_in[0];
    const float* ed  = (const float*)d_in[1];
    const float* E   = (const float*)d_in[2];
    const float* nu  = (const float*)d_in[3];
    const float* Ew1 = (const float*)d_in[4];
    const float* Eb1 = (const float*)d_in[5];
    const float* Ew2 = (const float*)d_in[6];
    const float* Eb2 = (const float*)d_in[7];
    const float* nw1 = (const float*)d_in[8];
    const float* nb1 = (const float*)d_in[9];
    const float* nw2 = (const float*)d_in[10];
    const float* nb2 = (const float*)d_in[11];
    const float* bw1 = (const float*)d_in[12];
    const float* bb1 = (const float*)d_in[13];
    const float* bw2 = (const float*)d_in[14];
    const float* bb2 = (const float*)d_in[15];

    int B = in_sizes[2] / M_;                       // 32768

    char* ws = (char*)d_ws;
    __hip_bfloat16* Xt   = (__hip_bfloat16*)ws;                                   // B*1024*2 bytes
    __hip_bfloat16* Wswz = (__hip_bfloat16*)(ws + (size_t)B * K_PAD * 2);         // 786432 bytes
    float* Emod = (float*)(ws + (size_t)B * K_PAD * 2 + (size_t)K_PAD * NTOT * 2);
    float* nuv  = Emod + B;
    float* beta = nuv + B;

    long long nx = (long long)B * K_PAD;
    build_x<<<(int)((nx + 255) / 256), 256, 0, stream>>>(E, nu, Xt, B);
    build_w<<<(K_PAD * NTOT + 255) / 256, 256, 0, stream>>>(Ew1, bw1, nw1, Wswz);
    mlp_gemm<<<B / 64, 256, 0, stream>>>(Xt, Wswz, Eb1, bb1, nb1, Ew2, bw2, nw2,
                                         Eb2, bb2, nb2, Emod, nuv, beta, B);
    float* stress = (float*)d_out;
    float* xiout  = stress + (size_t)B * T_;
    scan_k<<<B / 4, 256, 0, stream>>>(e, ed, Emod, nuv, beta, stress, xiout);
}

// Round 3
// 222.346 us; speedup vs baseline: 1.6381x; 1.0174x over previous
//
#include <hip/hip_runtime.h>
#include <hip/hip_bf16.h>

#define M_ 501
#define K_PAD 1024
#define NTOT 384
#define T_ 512
#define DT_ 0.01f

typedef __attribute__((ext_vector_type(8))) __bf16 bf16x8;
typedef __attribute__((ext_vector_type(4))) float f32x4;
typedef __attribute__((ext_vector_type(8))) unsigned short u16x8;

// ---------------- P1: pack X k-major tiled: Xt[k0][b][kk], k = k0*32+kk ------
// Vectorized: each (wave,s) task handles 64 rows x 16 k. Rows sit at 501-float
// stride (odd), so load 5 aligned float4 covering the 20-float window and
// shift-extract by o = start&3 with branch-free selects (static indices only).
__global__ __launch_bounds__(256) void build_x2(const float* __restrict__ E,
                                                const float* __restrict__ nu,
                                                __hip_bfloat16* __restrict__ Xt, int B) {
    const int lane = threadIdx.x & 63;
    const int w = threadIdx.x >> 6;              // 0..3
    const int bgrp = blockIdx.x >> 2;
    const int sgrp = blockIdx.x & 3;
    const int b = bgrp * 64 + lane;

    #pragma unroll
    for (int i = 0; i < 4; i++) {
        const int s = sgrp * 16 + i * 4 + w;     // 0..63, wave-uniform
        float f[16];
        if (s == 63) {
            #pragma unroll
            for (int j = 0; j < 16; j++) f[j] = 0.f;
        } else if (s == 31 || s == 62) {
            // boundary slots: scalar gather (wave-uniform branch, rare)
            #pragma unroll
            for (int j = 0; j < 16; j++) {
                int k = s * 16 + j;
                f[j] = (k < M_)     ? E[(size_t)b * M_ + k]
                     : (k < 2*M_)   ? nu[(size_t)b * M_ + (k - M_)] : 0.f;
            }
        } else {
            const float* src = (s < 31) ? E : nu;
            const int start = b * M_ + s * 16 - ((s < 31) ? 0 : M_);
            const int o = start & 3;
            const float4* p = (const float4*)(src + (start & ~3));
            float4 A0 = p[0], A1 = p[1], A2 = p[2], A3 = p[3], A4 = p[4];
            float gg[20] = {A0.x,A0.y,A0.z,A0.w, A1.x,A1.y,A1.z,A1.w,
                            A2.x,A2.y,A2.z,A2.w, A3.x,A3.y,A3.z,A3.w,
                            A4.x,A4.y,A4.z,A4.w};
            const bool o2 = (o & 2) != 0, o1 = (o & 1) != 0;
            float t[18];
            #pragma unroll
            for (int j = 0; j < 18; j++) t[j] = o2 ? gg[j + 2] : gg[j];
            #pragma unroll
            for (int j = 0; j < 16; j++) f[j] = o1 ? t[j + 1] : t[j];
        }
        u16x8 lo, hi;
        #pragma unroll
        for (int j = 0; j < 8; j++) {
            __hip_bfloat16 a = __float2bfloat16(f[j]);
            __hip_bfloat16 bb = __float2bfloat16(f[j + 8]);
            lo[j] = *(unsigned short*)&a;
            hi[j] = *(unsigned short*)&bb;
        }
        __hip_bfloat16* dst = Xt + ((size_t)(s >> 1) * B + b) * 32 + (s & 1) * 16;
        *(u16x8*)dst = lo;
        *((u16x8*)(dst + 8)) = hi;
    }
}

// ---------------- P2: pack W1comb (1024 x 384) pre-swizzled into MFMA B-fragment order
__global__ void build_w(const float* __restrict__ Ew1, const float* __restrict__ bw1,
                        const float* __restrict__ nw1, __hip_bfloat16* __restrict__ Wswz) {
    int idx = blockIdx.x * 256 + threadIdx.x;       // total 32*24*64*8 = 393216
    if (idx >= 32 * 24 * 64 * 8) return;
    int e  = idx & 7;
    int l  = (idx >> 3) & 63;
    int t  = idx >> 9;                               // k0*24 + nt
    int nt = t % 24, k0 = t / 24;
    int k  = k0 * 32 + ((l >> 4) << 3) + e;
    int n  = nt * 16 + (l & 15);
    float v = 0.f;
    if (n < 128)      { if (k < 2*M_)             v = Ew1[k * 128 + n]; }
    else if (n < 256) { if (k < 2*M_)             v = bw1[k * 128 + (n - 128)]; }
    else              { if (k >= M_ && k < 2*M_)  v = nw1[(k - M_) * 128 + (n - 256)]; }
    Wswz[idx] = __float2bfloat16(v);
}

// ---------------- GEMM + fused second layer ---------------------------------
// Block = 8 waves = 64 rows. Each wave: all 64 rows (4 A-frags) x 48 cols (3 n-tiles).
// 512 threads, 4 waves/SIMD for latency hiding (VGPR capped at 128).
__global__ __launch_bounds__(512, 4) void mlp_gemm(
    const __hip_bfloat16* __restrict__ Xt, const __hip_bfloat16* __restrict__ Wswz,
    const float* __restrict__ Eb1, const float* __restrict__ bb1, const float* __restrict__ nb1,
    const float* __restrict__ Ew2, const float* __restrict__ bw2, const float* __restrict__ nw2,
    const float* __restrict__ Eb2, const float* __restrict__ bb2, const float* __restrict__ nb2,
    float* __restrict__ Emod, float* __restrict__ nuv, float* __restrict__ beta, int B)
{
    const int wid = threadIdx.x >> 6, l = threadIdx.x & 63;
    const int c = l & 15, g = l >> 4;
    const int brow = blockIdx.x * 64;

    __shared__ float lds_s[3][64];
    if (threadIdx.x < 192) ((float*)lds_s)[threadIdx.x] = 0.f;

    const bf16x8* wbase = (const bf16x8*)Wswz;

    f32x4 acc[4][3];
    #pragma unroll
    for (int mi = 0; mi < 4; mi++)
        #pragma unroll
        for (int nt = 0; nt < 3; nt++) acc[mi][nt] = (f32x4){0.f, 0.f, 0.f, 0.f};

    for (int k0 = 0; k0 < 32; k0++) {
        bf16x8 af[4];
        #pragma unroll
        for (int mi = 0; mi < 4; mi++)
            af[mi] = *(const bf16x8*)(Xt + ((size_t)k0 * B + brow + mi * 16 + c) * 32 + g * 8);
        #pragma unroll
        for (int nt = 0; nt < 3; nt++) {
            bf16x8 bfrag = wbase[(size_t)(k0 * 24 + wid * 3 + nt) * 64 + l];
            #pragma unroll
            for (int mi = 0; mi < 4; mi++)
                acc[mi][nt] = __builtin_amdgcn_mfma_f32_16x16x32_bf16(af[mi], bfrag, acc[mi][nt], 0, 0, 0);
        }
    }
    __syncthreads();

    // Epilogue: h = softplus(acc + b1); dot with w2 per MLP; cross-wave via LDS atomics.
    #pragma unroll
    for (int nt = 0; nt < 3; nt++) {
        int gnt = wid * 3 + nt;
        int mlp = gnt >> 3;                          // 0:E 1:beta 2:nu
        int jj = (gnt * 16 + c) & 127;
        float b1 = (mlp == 0) ? Eb1[jj] : (mlp == 1) ? bb1[jj] : nb1[jj];
        float w2 = (mlp == 0) ? Ew2[jj] : (mlp == 1) ? bw2[jj] : nw2[jj];
        #pragma unroll
        for (int mi = 0; mi < 4; mi++) {
            #pragma unroll
            for (int r = 0; r < 4; r++) {
                float x = acc[mi][nt][r] + b1;
                float h = fmaxf(x, 0.f) + __logf(1.f + __expf(-fabsf(x)));
                float v = h * w2;
                v += __shfl_xor(v, 1);
                v += __shfl_xor(v, 2);
                v += __shfl_xor(v, 4);
                v += __shfl_xor(v, 8);
                if (c == 0) atomicAdd(&lds_s[mlp][mi * 16 + g * 4 + r], v);
            }
        }
    }
    __syncthreads();

    if (threadIdx.x < 64) {
        int b = brow + threadIdx.x;
        float s0 = lds_s[0][threadIdx.x], s1 = lds_s[1][threadIdx.x], s2 = lds_s[2][threadIdx.x];
        Emod[b] = __expf(s0 + Eb2[0]);
        float mb = s1 + bb2[0];
        beta[b]  = mb * mb * (1.f / 40000.f);
        float mn = s2 + nb2[0];
        nuv[b]   = __expf(mn * mn * (1.f / 40000.f));
    }
}

// ---------------- Scan: one wave per row b, lane i owns t in [8i, 8i+8) ------
__global__ __launch_bounds__(256) void scan_k(
    const float* __restrict__ e, const float* __restrict__ ed,
    const float* __restrict__ Emod, const float* __restrict__ nuv, const float* __restrict__ beta,
    float* __restrict__ stress, float* __restrict__ xiout)
{
    int lane = threadIdx.x & 63;
    int b = blockIdx.x * 4 + (threadIdx.x >> 6);
    float Em = Emod[b], nv = nuv[b], bt = beta[b];
    float cc = DT_ * bt;
    float a  = 1.f - cc;

    size_t base = (size_t)b * T_ + (size_t)lane * 8;
    float4 e0 = *(const float4*)(e + base),  e1 = *(const float4*)(e + base + 4);
    float4 d0 = *(const float4*)(ed + base), d1 = *(const float4*)(ed + base + 4);
    float ev[8] = {e0.x, e0.y, e0.z, e0.w, e1.x, e1.y, e1.z, e1.w};
    float dv[8] = {d0.x, d0.y, d0.z, d0.w, d1.x, d1.y, d1.z, d1.w};

    float S = 0.f;
    #pragma unroll
    for (int j = 0; j < 8; j++) S = a * S + ev[j];
    float a2 = a * a, a4 = a2 * a2, A = a4 * a4;

    #pragma unroll
    for (int d = 1; d < 64; d <<= 1) {
        float Su = __shfl_up(S, d);
        float Au = __shfl_up(A, d);
        if (lane >= d) { S = Su * A + S; A = Au * A; }
    }
    float Sp = __shfl_up(S, 1);
    float xi = (lane == 0) ? 0.f : cc * Sp;

    float st[8], xo[8];
    #pragma unroll
    for (int j = 0; j < 8; j++) {
        xo[j] = xi;
        float q = ev[j] - xi;
        st[j] = Em * ev[j] + q + nv * dv[j];
        xi = xi + cc * q;
    }
    *(float4*)(stress + base)     = (float4){st[0], st[1], st[2], st[3]};
    *(float4*)(stress + base + 4) = (float4){st[4], st[5], st[6], st[7]};
    *(float4*)(xiout + base)      = (float4){xo[0], xo[1], xo[2], xo[3]};
    *(float4*)(xiout + base + 4)  = (float4){xo[4], xo[5], xo[6], xo[7]};
}

extern "C" void kernel_launch(void* const* d_in, const int* in_sizes, int n_in,
                              void* d_out, int out_size, void* d_ws, size_t ws_size,
                              hipStream_t stream) {
    const float* e   = (const float*)d_in[0];
    const float* ed  = (const float*)d_in[1];
    const float* E   = (const float*)d_in[2];
    const float* nu  = (const float*)d_in[3];
    const float* Ew1 = (const float*)d_in[4];
    const float* Eb1 = (const float*)d_in[5];
    const float* Ew2 = (const float*)d_in[6];
    const float* Eb2 = (const float*)d_in[7];
    const float* nw1 = (const float*)d_in[8];
    const float* nb1 = (const float*)d_in[9];
    const float* nw2 = (const float*)d_in[10];
    const float* nb2 = (const float*)d_in[11];
    const float* bw1 = (const float*)d_in[12];
    const float* bb1 = (const float*)d_in[13];
    const float* bw2 = (const float*)d_in[14];
    const float* bb2 = (const float*)d_in[15];

    int B = in_sizes[2] / M_;                       // 32768

    char* ws = (char*)d_ws;
    __hip_bfloat16* Xt   = (__hip_bfloat16*)ws;                                   // B*1024*2 bytes
    __hip_bfloat16* Wswz = (__hip_bfloat16*)(ws + (size_t)B * K_PAD * 2);         // 786432 bytes
    float* Emod = (float*)(ws + (size_t)B * K_PAD * 2 + (size_t)K_PAD * NTOT * 2);
    float* nuv  = Emod + B;
    float* beta = nuv + B;

    build_x2<<<(B / 64) * 4, 256, 0, stream>>>(E, nu, Xt, B);
    build_w<<<(K_PAD * NTOT + 255) / 256, 256, 0, stream>>>(Ew1, bw1, nw1, Wswz);
    mlp_gemm<<<B / 64, 512, 0, stream>>>(Xt, Wswz, Eb1, bb1, nb1, Ew2, bw2, nw2,
                                         Eb2, bb2, nb2, Emod, nuv, beta, B);
    float* stress = (float*)d_out;
    float* xiout  = stress + (size_t)B * T_;
    scan_k<<<B / 4, 256, 0, stream>>>(e, ed, Emod, nuv, beta, stress, xiout);
}

// Round 4
// 174.782 us; speedup vs baseline: 2.0839x; 1.2721x over previous
//
#include <hip/hip_runtime.h>
#include <hip/hip_bf16.h>

#define M_ 501
#define K_PAD 1024
#define NTOT 384
#define T_ 512
#define DT_ 0.01f

typedef __attribute__((ext_vector_type(8))) __bf16 bf16x8;
typedef __attribute__((ext_vector_type(4))) float f32x4;

static __device__ __forceinline__ unsigned int pack2(float a, float b) {
    __hip_bfloat16 ha = __float2bfloat16(a);
    __hip_bfloat16 hb = __float2bfloat16(b);
    unsigned short ua = __builtin_bit_cast(unsigned short, ha);
    unsigned short ub = __builtin_bit_cast(unsigned short, hb);
    return (unsigned int)ua | ((unsigned int)ub << 16);
}

// ---------------- P1: pack X k-major tiled: Xt[k0][b][kk], k = k0*32+kk ------
// NO ARRAYS anywhere (named scalars only) so nothing can be demoted to LDS/scratch.
__global__ __launch_bounds__(256) void build_x3(const float* __restrict__ E,
                                                const float* __restrict__ nu,
                                                __hip_bfloat16* __restrict__ Xt, int B) {
    const int lane = threadIdx.x & 63;
    const int w = threadIdx.x >> 6;              // 0..3
    const int bgrp = blockIdx.x >> 2;
    const int sgrp = blockIdx.x & 3;
    const int b = bgrp * 64 + lane;

    #pragma unroll
    for (int i = 0; i < 4; i++) {
        const int s = sgrp * 16 + i * 4 + w;     // 0..63, wave-uniform
        float f0,f1,f2,f3,f4,f5,f6,f7,f8,f9,f10,f11,f12,f13,f14,f15;
        if (s == 63) {
            f0=f1=f2=f3=f4=f5=f6=f7=f8=f9=f10=f11=f12=f13=f14=f15=0.f;
        } else if (s == 31) {
            const float* eb = E  + (size_t)b * M_;
            const float* nb = nu + (size_t)b * M_;
            f0=eb[496]; f1=eb[497]; f2=eb[498]; f3=eb[499]; f4=eb[500];
            f5=nb[0]; f6=nb[1]; f7=nb[2]; f8=nb[3]; f9=nb[4]; f10=nb[5];
            f11=nb[6]; f12=nb[7]; f13=nb[8]; f14=nb[9]; f15=nb[10];
        } else if (s == 62) {
            const float* nb = nu + (size_t)b * M_;
            f0=nb[491]; f1=nb[492]; f2=nb[493]; f3=nb[494]; f4=nb[495];
            f5=nb[496]; f6=nb[497]; f7=nb[498]; f8=nb[499]; f9=nb[500];
            f10=f11=f12=f13=f14=f15=0.f;
        } else {
            const float* src = (s < 31) ? E : nu;
            const int start = b * M_ + s * 16 - ((s < 31) ? 0 : M_);
            const int o = start & 3;
            const float4* p = (const float4*)(src + (start & ~3));
            float4 A0 = p[0], A1 = p[1], A2 = p[2], A3 = p[3], A4 = p[4];
            float g0=A0.x, g1=A0.y, g2=A0.z, g3=A0.w,
                  g4=A1.x, g5=A1.y, g6=A1.z, g7=A1.w,
                  g8=A2.x, g9=A2.y, g10=A2.z, g11=A2.w,
                  g12=A3.x, g13=A3.y, g14=A3.z, g15=A3.w,
                  g16=A4.x, g17=A4.y, g18=A4.z;
            const bool o2 = (o & 2) != 0, o1 = (o & 1) != 0;
            float u0  = o2?g2:g0,   u1  = o2?g3:g1,   u2  = o2?g4:g2,   u3  = o2?g5:g3,
                  u4  = o2?g6:g4,   u5  = o2?g7:g5,   u6  = o2?g8:g6,   u7  = o2?g9:g7,
                  u8  = o2?g10:g8,  u9  = o2?g11:g9,  u10 = o2?g12:g10, u11 = o2?g13:g11,
                  u12 = o2?g14:g12, u13 = o2?g15:g13, u14 = o2?g16:g14, u15 = o2?g17:g15,
                  u16_= o2?g18:g16;
            f0  = o1?u1:u0;    f1  = o1?u2:u1;    f2  = o1?u3:u2;    f3  = o1?u4:u3;
            f4  = o1?u5:u4;    f5  = o1?u6:u5;    f6  = o1?u7:u6;    f7  = o1?u8:u7;
            f8  = o1?u9:u8;    f9  = o1?u10:u9;   f10 = o1?u11:u10;  f11 = o1?u12:u11;
            f12 = o1?u13:u12;  f13 = o1?u14:u13;  f14 = o1?u15:u14;  f15 = o1?u16_:u15;
        }
        uint4 lo, hi;
        lo.x = pack2(f0, f1);  lo.y = pack2(f2, f3);
        lo.z = pack2(f4, f5);  lo.w = pack2(f6, f7);
        hi.x = pack2(f8, f9);  hi.y = pack2(f10, f11);
        hi.z = pack2(f12, f13); hi.w = pack2(f14, f15);
        __hip_bfloat16* dst = Xt + ((size_t)(s >> 1) * B + b) * 32 + (s & 1) * 16;
        *(uint4*)dst = lo;
        *((uint4*)(dst + 8)) = hi;
    }
}

// ---------------- P2: pack W1comb (1024 x 384) pre-swizzled into MFMA B-fragment order
__global__ void build_w(const float* __restrict__ Ew1, const float* __restrict__ bw1,
                        const float* __restrict__ nw1, __hip_bfloat16* __restrict__ Wswz) {
    int idx = blockIdx.x * 256 + threadIdx.x;       // total 32*24*64*8 = 393216
    if (idx >= 32 * 24 * 64 * 8) return;
    int e  = idx & 7;
    int l  = (idx >> 3) & 63;
    int t  = idx >> 9;                               // k0*24 + nt
    int nt = t % 24, k0 = t / 24;
    int k  = k0 * 32 + ((l >> 4) << 3) + e;
    int n  = nt * 16 + (l & 15);
    float v = 0.f;
    if (n < 128)      { if (k < 2*M_)             v = Ew1[k * 128 + n]; }
    else if (n < 256) { if (k < 2*M_)             v = bw1[k * 128 + (n - 128)]; }
    else              { if (k >= M_ && k < 2*M_)  v = nw1[(k - M_) * 128 + (n - 256)]; }
    Wswz[idx] = __float2bfloat16(v);
}

// ---------------- GEMM + fused second layer ---------------------------------
// Block = 8 waves = 64 rows. Each wave: all 64 rows (4 A-frags) x 48 cols (3 n-tiles).
__global__ __launch_bounds__(512, 4) void mlp_gemm(
    const __hip_bfloat16* __restrict__ Xt, const __hip_bfloat16* __restrict__ Wswz,
    const float* __restrict__ Eb1, const float* __restrict__ bb1, const float* __restrict__ nb1,
    const float* __restrict__ Ew2, const float* __restrict__ bw2, const float* __restrict__ nw2,
    const float* __restrict__ Eb2, const float* __restrict__ bb2, const float* __restrict__ nb2,
    float* __restrict__ Emod, float* __restrict__ nuv, float* __restrict__ beta, int B)
{
    const int wid = threadIdx.x >> 6, l = threadIdx.x & 63;
    const int c = l & 15, g = l >> 4;
    const int brow = blockIdx.x * 64;

    __shared__ float lds_s[3][64];
    if (threadIdx.x < 192) ((float*)lds_s)[threadIdx.x] = 0.f;

    const bf16x8* wbase = (const bf16x8*)Wswz;

    f32x4 acc[4][3];
    #pragma unroll
    for (int mi = 0; mi < 4; mi++)
        #pragma unroll
        for (int nt = 0; nt < 3; nt++) acc[mi][nt] = (f32x4){0.f, 0.f, 0.f, 0.f};

    for (int k0 = 0; k0 < 32; k0++) {
        bf16x8 af[4];
        #pragma unroll
        for (int mi = 0; mi < 4; mi++)
            af[mi] = *(const bf16x8*)(Xt + ((size_t)k0 * B + brow + mi * 16 + c) * 32 + g * 8);
        #pragma unroll
        for (int nt = 0; nt < 3; nt++) {
            bf16x8 bfrag = wbase[(size_t)(k0 * 24 + wid * 3 + nt) * 64 + l];
            #pragma unroll
            for (int mi = 0; mi < 4; mi++)
                acc[mi][nt] = __builtin_amdgcn_mfma_f32_16x16x32_bf16(af[mi], bfrag, acc[mi][nt], 0, 0, 0);
        }
    }
    __syncthreads();

    #pragma unroll
    for (int nt = 0; nt < 3; nt++) {
        int gnt = wid * 3 + nt;
        int mlp = gnt >> 3;                          // 0:E 1:beta 2:nu
        int jj = (gnt * 16 + c) & 127;
        float b1 = (mlp == 0) ? Eb1[jj] : (mlp == 1) ? bb1[jj] : nb1[jj];
        float w2 = (mlp == 0) ? Ew2[jj] : (mlp == 1) ? bw2[jj] : nw2[jj];
        #pragma unroll
        for (int mi = 0; mi < 4; mi++) {
            #pragma unroll
            for (int r = 0; r < 4; r++) {
                float x = acc[mi][nt][r] + b1;
                float h = fmaxf(x, 0.f) + __logf(1.f + __expf(-fabsf(x)));
                float v = h * w2;
                v += __shfl_xor(v, 1);
                v += __shfl_xor(v, 2);
                v += __shfl_xor(v, 4);
                v += __shfl_xor(v, 8);
                if (c == 0) atomicAdd(&lds_s[mlp][mi * 16 + g * 4 + r], v);
            }
        }
    }
    __syncthreads();

    if (threadIdx.x < 64) {
        int b = brow + threadIdx.x;
        float s0 = lds_s[0][threadIdx.x], s1 = lds_s[1][threadIdx.x], s2 = lds_s[2][threadIdx.x];
        Emod[b] = __expf(s0 + Eb2[0]);
        float mb = s1 + bb2[0];
        beta[b]  = mb * mb * (1.f / 40000.f);
        float mn = s2 + nb2[0];
        nuv[b]   = __expf(mn * mn * (1.f / 40000.f));
    }
}

// ---------------- Scan: one wave per row b, lane i owns t in [8i, 8i+8) ------
__global__ __launch_bounds__(256) void scan_k(
    const float* __restrict__ e, const float* __restrict__ ed,
    const float* __restrict__ Emod, const float* __restrict__ nuv, const float* __restrict__ beta,
    float* __restrict__ stress, float* __restrict__ xiout)
{
    int lane = threadIdx.x & 63;
    int b = blockIdx.x * 4 + (threadIdx.x >> 6);
    float Em = Emod[b], nv = nuv[b], bt = beta[b];
    float cc = DT_ * bt;
    float a  = 1.f - cc;

    size_t base = (size_t)b * T_ + (size_t)lane * 8;
    float4 e0 = *(const float4*)(e + base),  e1 = *(const float4*)(e + base + 4);
    float4 d0 = *(const float4*)(ed + base), d1 = *(const float4*)(ed + base + 4);
    float ev[8] = {e0.x, e0.y, e0.z, e0.w, e1.x, e1.y, e1.z, e1.w};
    float dv[8] = {d0.x, d0.y, d0.z, d0.w, d1.x, d1.y, d1.z, d1.w};

    float S = 0.f;
    #pragma unroll
    for (int j = 0; j < 8; j++) S = a * S + ev[j];
    float a2 = a * a, a4 = a2 * a2, A = a4 * a4;

    #pragma unroll
    for (int d = 1; d < 64; d <<= 1) {
        float Su = __shfl_up(S, d);
        float Au = __shfl_up(A, d);
        if (lane >= d) { S = Su * A + S; A = Au * A; }
    }
    float Sp = __shfl_up(S, 1);
    float xi = (lane == 0) ? 0.f : cc * Sp;

    float st[8], xo[8];
    #pragma unroll
    for (int j = 0; j < 8; j++) {
        xo[j] = xi;
        float q = ev[j] - xi;
        st[j] = Em * ev[j] + q + nv * dv[j];
        xi = xi + cc * q;
    }
    *(float4*)(stress + base)     = (float4){st[0], st[1], st[2], st[3]};
    *(float4*)(stress + base + 4) = (float4){st[4], st[5], st[6], st[7]};
    *(float4*)(xiout + base)      = (float4){xo[0], xo[1], xo[2], xo[3]};
    *(float4*)(xiout + base + 4)  = (float4){xo[4], xo[5], xo[6], xo[7]};
}

extern "C" void kernel_launch(void* const* d_in, const int* in_sizes, int n_in,
                              void* d_out, int out_size, void* d_ws, size_t ws_size,
                              hipStream_t stream) {
    const float* e   = (const float*)d_in[0];
    const float* ed  = (const float*)d_in[1];
    const float* E   = (const float*)d_in[2];
    const float* nu  = (const float*)d_in[3];
    const float* Ew1 = (const float*)d_in[4];
    const float* Eb1 = (const float*)d_in[5];
    const float* Ew2 = (const float*)d_in[6];
    const float* Eb2 = (const float*)d_in[7];
    const float* nw1 = (const float*)d_in[8];
    const float* nb1 = (const float*)d_in[9];
    const float* nw2 = (const float*)d_in[10];
    const float* nb2 = (const float*)d_in[11];
    const float* bw1 = (const float*)d_in[12];
    const float* bb1 = (const float*)d_in[13];
    const float* bw2 = (const float*)d_in[14];
    const float* bb2 = (const float*)d_in[15];

    int B = in_sizes[2] / M_;                       // 32768

    char* ws = (char*)d_ws;
    __hip_bfloat16* Xt   = (__hip_bfloat16*)ws;                                   // B*1024*2 bytes
    __hip_bfloat16* Wswz = (__hip_bfloat16*)(ws + (size_t)B * K_PAD * 2);         // 786432 bytes
    float* Emod = (float*)(ws + (size_t)B * K_PAD * 2 + (size_t)K_PAD * NTOT * 2);
    float* nuv  = Emod + B;
    float* beta = nuv + B;

    build_x3<<<(B / 64) * 4, 256, 0, stream>>>(E, nu, Xt, B);
    build_w<<<(K_PAD * NTOT + 255) / 256, 256, 0, stream>>>(Ew1, bw1, nw1, Wswz);
    mlp_gemm<<<B / 64, 512, 0, stream>>>(Xt, Wswz, Eb1, bb1, nb1, Ew2, bw2, nw2,
                                         Eb2, bb2, nb2, Emod, nuv, beta, B);
    float* stress = (float*)d_out;
    float* xiout  = stress + (size_t)B * T_;
    scan_k<<<B / 4, 256, 0, stream>>>(e, ed, Emod, nuv, beta, stress, xiout);
}